// Round 1
// baseline (127.733 us; speedup 1.0000x reference)
//
#include <hip/hip_runtime.h>

#define NUM_PTS 1024
#define NBATCH 128
#define LATENT 32
#define BETA 0.1f
#define BLOCKS_PER_BATCH 2
#define THREADS 256

// One block handles half the points of one batch for each direction of the
// Chamfer min. Both full point sets staged in LDS as float4 (stride-4 pad ->
// single ds_read_b128 per point, wave-broadcast so no bank conflicts).
__global__ __launch_bounds__(THREADS) void chamfer_kernel(
    const float* __restrict__ recon_x,  // [B, N, 3]
    const float* __restrict__ x,        // [B, N, 3]
    float* __restrict__ out)
{
    __shared__ float4 sx[NUM_PTS];  // x points
    __shared__ float4 sy[NUM_PTS];  // recon points
    __shared__ float red[THREADS / 64];

    const int b    = blockIdx.x / BLOCKS_PER_BATCH;
    const int half = blockIdx.x % BLOCKS_PER_BATCH;
    const float* xb = x       + (size_t)b * NUM_PTS * 3;
    const float* yb = recon_x + (size_t)b * NUM_PTS * 3;

    for (int p = threadIdx.x; p < NUM_PTS; p += THREADS) {
        sx[p] = make_float4(xb[3 * p], xb[3 * p + 1], xb[3 * p + 2], 0.f);
        sy[p] = make_float4(yb[3 * p], yb[3 * p + 1], yb[3 * p + 2], 0.f);
    }
    __syncthreads();

    float local = 0.f;

    // ---- Pass A: for each x point i (this block's half), min over recon j
    //      == reference loss_2
    {
        const int i0 = half * (NUM_PTS / 2) + threadIdx.x;
        const int i1 = i0 + THREADS;
        const float4 a = sx[i0];
        const float4 c = sx[i1];
        float m0 = 1e30f, m1 = 1e30f;
#pragma unroll 8
        for (int j = 0; j < NUM_PTS; ++j) {
            const float4 q = sy[j];
            float d0x = a.x - q.x, d0y = a.y - q.y, d0z = a.z - q.z;
            float d1x = c.x - q.x, d1y = c.y - q.y, d1z = c.z - q.z;
            float d0 = d0x * d0x + d0y * d0y + d0z * d0z;
            float d1 = d1x * d1x + d1y * d1y + d1z * d1z;
            m0 = fminf(m0, d0);
            m1 = fminf(m1, d1);
        }
        local += m0 + m1;
    }

    // ---- Pass B: for each recon point j (this block's half), min over x i
    //      == reference loss_1
    {
        const int j0 = half * (NUM_PTS / 2) + threadIdx.x;
        const int j1 = j0 + THREADS;
        const float4 a = sy[j0];
        const float4 c = sy[j1];
        float m0 = 1e30f, m1 = 1e30f;
#pragma unroll 8
        for (int i = 0; i < NUM_PTS; ++i) {
            const float4 q = sx[i];
            float d0x = a.x - q.x, d0y = a.y - q.y, d0z = a.z - q.z;
            float d1x = c.x - q.x, d1y = c.y - q.y, d1z = c.z - q.z;
            float d0 = d0x * d0x + d0y * d0y + d0z * d0z;
            float d1 = d1x * d1x + d1y * d1y + d1z * d1z;
            m0 = fminf(m0, d0);
            m1 = fminf(m1, d1);
        }
        local += m0 + m1;
    }

    // ---- block reduction: wave shuffle -> LDS -> one atomic per block
    for (int off = 32; off > 0; off >>= 1)
        local += __shfl_down(local, off, 64);
    const int lane = threadIdx.x & 63;
    const int wv   = threadIdx.x >> 6;
    if (lane == 0) red[wv] = local;
    __syncthreads();
    if (threadIdx.x == 0) {
        float s = 0.f;
        for (int w = 0; w < THREADS / 64; ++w) s += red[w];
        atomicAdd(out, s * (1.0f / NUM_PTS));  // RE contribution
    }
}

// KLD = -0.5 * sum(1 + logvar - mu^2 - exp(logvar)); out += BETA * KLD / 32
__global__ __launch_bounds__(256) void kld_kernel(
    const float* __restrict__ mu,
    const float* __restrict__ logvar,
    float* __restrict__ out)
{
    __shared__ float red[4];
    float local = 0.f;
    for (int t = threadIdx.x; t < NBATCH * LATENT; t += 256) {
        float lv = logvar[t];
        float m  = mu[t];
        local += 1.0f + lv - m * m - expf(lv);
    }
    for (int off = 32; off > 0; off >>= 1)
        local += __shfl_down(local, off, 64);
    const int lane = threadIdx.x & 63;
    const int wv   = threadIdx.x >> 6;
    if (lane == 0) red[wv] = local;
    __syncthreads();
    if (threadIdx.x == 0) {
        float s = red[0] + red[1] + red[2] + red[3];
        atomicAdd(out, s * (-0.5f * BETA / (float)LATENT));
    }
}

extern "C" void kernel_launch(void* const* d_in, const int* in_sizes, int n_in,
                              void* d_out, int out_size, void* d_ws, size_t ws_size,
                              hipStream_t stream) {
    const float* recon_x = (const float*)d_in[0];
    const float* x       = (const float*)d_in[1];
    const float* mu      = (const float*)d_in[2];
    const float* logvar  = (const float*)d_in[3];
    float* out = (float*)d_out;

    // d_out is re-poisoned to 0xAA before every launch; zero it first.
    hipMemsetAsync(out, 0, sizeof(float), stream);

    chamfer_kernel<<<NBATCH * BLOCKS_PER_BATCH, THREADS, 0, stream>>>(recon_x, x, out);
    kld_kernel<<<1, 256, 0, stream>>>(mu, logvar, out);
}

// Round 2
// 113.292 us; speedup vs baseline: 1.1275x; 1.1275x over previous
//
#include <hip/hip_runtime.h>

#define NUM_PTS 1024
#define NBATCH 128
#define LATENT 32
#define THREADS 256
// out += chamfer/NUM_PTS + (-0.5*sum_kld)*BETA/LATENT
#define CHAMF_SCALE (1.0f / 1024.0f)
#define KLD_SCALE   (-0.5f * 0.1f / 32.0f)

typedef float f2 __attribute__((ext_vector_type(2)));

// One distance eval for 2 rows packed in f2 lanes (targets v_pk_fma_f32).
__device__ __forceinline__ void eval_pt(float qx, float qy, float qz,
                                        f2 vx, f2 vy, f2 vz, f2& mn)
{
    f2 dx = vx - qx;
    f2 dy = vy - qy;
    f2 dz = vz - qz;
    f2 d  = dx * dx + dy * dy + dz * dz;   // contract -> pk_fma
    mn.x = fminf(mn.x, d.x);
    mn.y = fminf(mn.y, d.y);
}

// 512 blocks: blockIdx = batch*4 + sub. sub 0,1 -> pass over x-rows (loss_2,
// min over recon); sub 2,3 -> recon-rows (loss_1, min over x). Each thread
// owns 2 rows; the q-point stream is wave-uniform -> SMEM/L1 broadcast, LDS
// pipe stays idle (it was the R0 co-bottleneck: 4 waves x 2048 ds_read_b128
// x 12cyc = 41us/CU vs 24us VALU).
__global__ __launch_bounds__(THREADS) void fused_kernel(
    const float* __restrict__ recon_x,  // [B, N, 3]
    const float* __restrict__ x,        // [B, N, 3]
    const float* __restrict__ mu,       // [B, 32]
    const float* __restrict__ logvar,   // [B, 32]
    float* __restrict__ out)
{
    const int b   = blockIdx.x >> 2;
    const int sub = blockIdx.x & 3;
    const bool passA    = (sub < 2);
    const int  halfbase = (sub & 1) * 512;

    const float* rp = (passA ? x : recon_x) + (size_t)b * NUM_PTS * 3;
    const float* qp = (passA ? recon_x : x) + (size_t)b * NUM_PTS * 3;

    // --- fused KLD: blocks 0..15 each cover 256 of the 4096 latent elems
    float kacc = 0.f;
    if (blockIdx.x < 16) {
        const int t = blockIdx.x * 256 + threadIdx.x;
        const float lv = logvar[t];
        const float m  = mu[t];
        kacc = 1.0f + lv - m * m - expf(lv);
    }

    // --- own rows (2 per thread), packed into f2 lanes
    const int r0 = halfbase + threadIdx.x;
    const int r1 = r0 + 256;
    f2 vx = { rp[3 * r0 + 0], rp[3 * r1 + 0] };
    f2 vy = { rp[3 * r0 + 1], rp[3 * r1 + 1] };
    f2 vz = { rp[3 * r0 + 2], rp[3 * r1 + 2] };

    // --- min over all 1024 q points; 3 uniform float4 loads per 4 points
    const float4* __restrict__ q4 = (const float4*)qp;  // batch base is 16B-aligned
    f2 mA = { 1e30f, 1e30f };
    f2 mB = { 1e30f, 1e30f };
#pragma unroll 2
    for (int t = 0; t < NUM_PTS / 4; ++t) {
        const float4 A = q4[3 * t + 0];
        const float4 B = q4[3 * t + 1];
        const float4 C = q4[3 * t + 2];
        eval_pt(A.x, A.y, A.z, vx, vy, vz, mA);
        eval_pt(A.w, B.x, B.y, vx, vy, vz, mB);
        eval_pt(B.z, B.w, C.x, vx, vy, vz, mA);
        eval_pt(C.y, C.z, C.w, vx, vy, vz, mB);
    }
    const float c0 = fminf(mA.x, mB.x);
    const float c1 = fminf(mA.y, mB.y);

    // --- per-thread scaled contribution, then block reduce -> one atomic
    float v = (c0 + c1) * CHAMF_SCALE + kacc * KLD_SCALE;

    for (int off = 32; off > 0; off >>= 1)
        v += __shfl_down(v, off, 64);

    __shared__ float red[THREADS / 64];
    const int lane = threadIdx.x & 63;
    const int wv   = threadIdx.x >> 6;
    if (lane == 0) red[wv] = v;
    __syncthreads();
    if (threadIdx.x == 0) {
        float s = 0.f;
        for (int w = 0; w < THREADS / 64; ++w) s += red[w];
        atomicAdd(out, s);
    }
}

extern "C" void kernel_launch(void* const* d_in, const int* in_sizes, int n_in,
                              void* d_out, int out_size, void* d_ws, size_t ws_size,
                              hipStream_t stream) {
    const float* recon_x = (const float*)d_in[0];
    const float* x       = (const float*)d_in[1];
    const float* mu      = (const float*)d_in[2];
    const float* logvar  = (const float*)d_in[3];
    float* out = (float*)d_out;

    // d_out is re-poisoned to 0xAA before every replay; zero it first.
    hipMemsetAsync(out, 0, sizeof(float), stream);

    fused_kernel<<<NBATCH * 4, THREADS, 0, stream>>>(recon_x, x, mu, logvar, out);
}

// Round 3
// 110.841 us; speedup vs baseline: 1.1524x; 1.0221x over previous
//
#include <hip/hip_runtime.h>

#define NUM_PTS 1024
#define NBATCH 128
#define LATENT 32
#define THREADS 256
#define CHAMF_SCALE (1.0f / 1024.0f)
#define KLD_SCALE   (-0.5f * 0.1f / 32.0f)

// ws layout: float ws[2][4][NBATCH][NUM_PTS]  (dir, q-chunk, batch, row)
// = 4 MB. Every slot written exactly once by chamfer_part (no memset needed).
#define WS_DIR_STRIDE   (4 * NBATCH * NUM_PTS)   // 524288
#define WS_CHUNK_STRIDE (NBATCH * NUM_PTS)       // 131072

typedef float f2 __attribute__((ext_vector_type(2)));

// Distances for 2 rows (packed f2) vs one q point.
__device__ __forceinline__ f2 dist2(float qx, float qy, float qz,
                                    f2 vx, f2 vy, f2 vz)
{
    f2 dx = vx - qx;
    f2 dy = vy - qy;
    f2 dz = vz - qz;
    return dx * dx + dy * dy + dz * dz;   // pk_mul + 2 pk_fma
}

// 2048 blocks: blockIdx = batch*16 + sub; sub = dir(1b) | rowhalf(1b) | chunk(2b).
// dir 0: rows from x, min over recon (ref loss_2); dir 1: rows from recon (loss_1).
// Each thread owns 2 rows (f2-packed), scans a 256-point q-chunk, stores 2
// partial mins. 8 blocks/CU -> 8 waves/SIMD (R1 was grid-capped at 2: the
// 38%-VALUBusy latency hole). No LDS, no atomics, no syncthreads here.
__global__ __launch_bounds__(THREADS, 8) void chamfer_part(
    const float* __restrict__ recon_x,  // [B, N, 3]
    const float* __restrict__ x,        // [B, N, 3]
    float* __restrict__ ws)
{
    const int b       = blockIdx.x >> 4;
    const int sub     = blockIdx.x & 15;
    const int dir     = sub >> 3;
    const int rowhalf = (sub >> 2) & 1;
    const int chunk   = sub & 3;

    const float* rp = (dir == 0 ? x : recon_x) + (size_t)b * NUM_PTS * 3;
    const float* qp = (dir == 0 ? recon_x : x) + (size_t)b * NUM_PTS * 3
                      + chunk * 256 * 3;          // 3072B offset, 16B-aligned

    const int r0 = rowhalf * 512 + threadIdx.x;
    const int r1 = r0 + 256;
    const f2 vx = { rp[3 * r0 + 0], rp[3 * r1 + 0] };
    const f2 vy = { rp[3 * r0 + 1], rp[3 * r1 + 1] };
    const f2 vz = { rp[3 * r0 + 2], rp[3 * r1 + 2] };

    const float4* __restrict__ q4 = (const float4*)qp;
    f2 m0 = { 1e30f, 1e30f };   // accumulators; q-pairs merged via v_min3
    f2 m1 = { 1e30f, 1e30f };
#pragma unroll 2
    for (int t = 0; t < 64; ++t) {                // 4 q points per iter
        const float4 A = q4[3 * t + 0];
        const float4 B = q4[3 * t + 1];
        const float4 C = q4[3 * t + 2];
        const f2 dA = dist2(A.x, A.y, A.z, vx, vy, vz);
        const f2 dB = dist2(A.w, B.x, B.y, vx, vy, vz);
        const f2 dC = dist2(B.z, B.w, C.x, vx, vy, vz);
        const f2 dD = dist2(C.y, C.z, C.w, vx, vy, vz);
        m0.x = fminf(fminf(m0.x, dA.x), dB.x);    // -> v_min3_f32
        m0.y = fminf(fminf(m0.y, dA.y), dB.y);
        m1.x = fminf(fminf(m1.x, dC.x), dD.x);
        m1.y = fminf(fminf(m1.y, dC.y), dD.y);
    }
    const float c0 = fminf(m0.x, m1.x);
    const float c1 = fminf(m0.y, m1.y);

    float* dst = ws + dir * WS_DIR_STRIDE + chunk * WS_CHUNK_STRIDE
                 + b * NUM_PTS;
    dst[r0] = c0;   // coalesced, each slot written exactly once
    dst[r1] = c1;
}

// Combine 4 chunk-partials per row, sum everything, fold in KLD.
// grid = 1024 blocks x 256 threads, one (dir,batch,row) slot per thread.
__global__ __launch_bounds__(THREADS) void reduce_kernel(
    const float* __restrict__ ws,
    const float* __restrict__ mu,
    const float* __restrict__ logvar,
    float* __restrict__ out)
{
    const int s   = blockIdx.x * THREADS + threadIdx.x;  // 0..262143
    const int dir = s >> 17;
    const int rem = s & 131071;                          // batch*1024 + row

    const float* p = ws + dir * WS_DIR_STRIDE + rem;
    const float m = fminf(fminf(p[0], p[WS_CHUNK_STRIDE]),
                          fminf(p[2 * WS_CHUNK_STRIDE], p[3 * WS_CHUNK_STRIDE]));
    float v = m * CHAMF_SCALE;

    if (blockIdx.x < 16) {                               // 16*256 = 4096 latents
        const int t = blockIdx.x * THREADS + threadIdx.x;
        const float lv = logvar[t];
        const float mm = mu[t];
        v += (1.0f + lv - mm * mm - expf(lv)) * KLD_SCALE;
    }

    for (int off = 32; off > 0; off >>= 1)
        v += __shfl_down(v, off, 64);

    __shared__ float red[THREADS / 64];
    const int lane = threadIdx.x & 63;
    const int wv   = threadIdx.x >> 6;
    if (lane == 0) red[wv] = v;
    __syncthreads();
    if (threadIdx.x == 0) {
        float sum = 0.f;
        for (int w = 0; w < THREADS / 64; ++w) sum += red[w];
        atomicAdd(out, sum);
    }
}

extern "C" void kernel_launch(void* const* d_in, const int* in_sizes, int n_in,
                              void* d_out, int out_size, void* d_ws, size_t ws_size,
                              hipStream_t stream) {
    const float* recon_x = (const float*)d_in[0];
    const float* x       = (const float*)d_in[1];
    const float* mu      = (const float*)d_in[2];
    const float* logvar  = (const float*)d_in[3];
    float* out = (float*)d_out;
    float* ws  = (float*)d_ws;   // needs 4 MB

    // d_out re-poisoned before every replay; zero the single accumulator.
    hipMemsetAsync(out, 0, sizeof(float), stream);

    chamfer_part<<<NBATCH * 16, THREADS, 0, stream>>>(recon_x, x, ws);
    reduce_kernel<<<1024, THREADS, 0, stream>>>(ws, mu, logvar, out);
}

// Round 4
// 109.119 us; speedup vs baseline: 1.1706x; 1.0158x over previous
//
#include <hip/hip_runtime.h>

#define NUM_PTS 1024
#define NBATCH 128
#define THREADS 256
#define NCHUNK 8                          // q-chunks per direction
#define CHUNK_PTS (NUM_PTS / NCHUNK)      // 128
#define CHAMF_SCALE (1.0f / 1024.0f)
#define KLD_SCALE   (-0.5f * 0.1f / 32.0f)

// ws: float [2][NCHUNK][NBATCH][NUM_PTS] = 8 MB of per-(dir,chunk) row partials,
// each = r2_row + min_over_chunk(q2 - 2 v.q). Every slot written exactly once.
#define WS_CHUNK_STRIDE (NBATCH * NUM_PTS)          // 131072
#define WS_DIR_STRIDE   (NCHUNK * WS_CHUNK_STRIDE)  // 1048576

// Evaluate one q point against 4 rows: t[r] = q2 - 2*v_r.q  (dot form; r2 is
// hoisted out of the min and added at the store). vx2 = -2*x etc.
__device__ __forceinline__ void qeval(float qx, float qy, float qz,
                                      const float* vx2, const float* vy2,
                                      const float* vz2, float* t)
{
    float q2 = qx * qx;
    q2 = fmaf(qy, qy, q2);
    q2 = fmaf(qz, qz, q2);
#pragma unroll
    for (int r = 0; r < 4; ++r)
        t[r] = fmaf(vx2[r], qx, fmaf(vy2[r], qy, fmaf(vz2[r], qz, q2)));
}

// 2048 blocks: blockIdx = b*16 + dir*8 + chunk. One block = all 1024 rows of
// (batch, dir) scanned against one 128-point q-chunk. 8 blocks/CU = 8
// waves/SIMD. R=4 rows/thread amortizes q2; q stream is wave-uniform ->
// s_load_dwordx4 (SGPRs), explicit 3-float4 register prefetch.
__global__ __launch_bounds__(THREADS, 8) void chamfer_part(
    const float* __restrict__ recon_x,  // [B, N, 3]
    const float* __restrict__ x,        // [B, N, 3]
    float* __restrict__ ws)
{
    const int b     = blockIdx.x >> 4;
    const int sub   = blockIdx.x & 15;
    const int dir   = sub >> 3;
    const int chunk = sub & 7;

    const float* rp = (dir == 0 ? x : recon_x) + (size_t)b * NUM_PTS * 3;
    const float* qp = (dir == 0 ? recon_x : x) + (size_t)b * NUM_PTS * 3
                      + chunk * CHUNK_PTS * 3;    // 1536 B offset, 16B-aligned

    // --- own 4 rows: pre-scale by -2, keep r2
    float vx2[4], vy2[4], vz2[4], r2[4], m[4];
#pragma unroll
    for (int k = 0; k < 4; ++k) {
        const int r = threadIdx.x + 256 * k;
        const float px = rp[3 * r + 0];
        const float py = rp[3 * r + 1];
        const float pz = rp[3 * r + 2];
        r2[k]  = fmaf(px, px, fmaf(py, py, pz * pz));
        vx2[k] = -2.0f * px;
        vy2[k] = -2.0f * py;
        vz2[k] = -2.0f * pz;
        m[k]   = 1e30f;
    }

    // --- scan 128 q points: 32 iters x 4 qpts (3 float4), prefetched
    const float4* __restrict__ q4 = (const float4*)qp;
    float4 A = q4[0], B = q4[1], C = q4[2];
    for (int t = 0; t < 32; ++t) {
        const int nt = (t < 31) ? t + 1 : 0;      // last prefetch unused
        const float4 An = q4[3 * nt + 0];
        const float4 Bn = q4[3 * nt + 1];
        const float4 Cn = q4[3 * nt + 2];

        float t0[4], t1[4], t2[4], t3[4];
        qeval(A.x, A.y, A.z, vx2, vy2, vz2, t0);
        qeval(A.w, B.x, B.y, vx2, vy2, vz2, t1);
        qeval(B.z, B.w, C.x, vx2, vy2, vz2, t2);
        qeval(C.y, C.z, C.w, vx2, vy2, vz2, t3);
#pragma unroll
        for (int r = 0; r < 4; ++r) {
            m[r] = fminf(fminf(m[r], t0[r]), t1[r]);   // v_min3_f32
            m[r] = fminf(fminf(m[r], t2[r]), t3[r]);
        }
        A = An; B = Bn; C = Cn;
    }

    // --- store per-row partial (r2 added here; min across chunks commutes
    //     with the constant shift up to 1 ulp)
    float* dst = ws + dir * WS_DIR_STRIDE + chunk * WS_CHUNK_STRIDE
                 + b * NUM_PTS;
#pragma unroll
    for (int k = 0; k < 4; ++k)
        dst[threadIdx.x + 256 * k] = r2[k] + m[k];     // coalesced
}

// Min-combine the 8 chunk partials per row, sum all rows, fold in KLD.
// 1024 blocks x 256 threads: one (dir,batch,row) slot per thread.
__global__ __launch_bounds__(THREADS) void reduce_kernel(
    const float* __restrict__ ws,
    const float* __restrict__ mu,
    const float* __restrict__ logvar,
    float* __restrict__ out)
{
    const int s   = blockIdx.x * THREADS + threadIdx.x;  // 0..262143
    const int dir = s >> 17;
    const int rem = s & 131071;                          // batch*1024 + row

    const float* p = ws + dir * WS_DIR_STRIDE + rem;
    float mn = p[0];
#pragma unroll
    for (int c = 1; c < NCHUNK; ++c)
        mn = fminf(mn, p[c * WS_CHUNK_STRIDE]);
    float v = mn * CHAMF_SCALE;

    if (blockIdx.x < 16) {                               // 16*256 = 4096 latents
        const int t = blockIdx.x * THREADS + threadIdx.x;
        const float lv = logvar[t];
        const float mm = mu[t];
        v += (1.0f + lv - mm * mm - expf(lv)) * KLD_SCALE;
    }

    for (int off = 32; off > 0; off >>= 1)
        v += __shfl_down(v, off, 64);

    __shared__ float red[THREADS / 64];
    const int lane = threadIdx.x & 63;
    const int wv   = threadIdx.x >> 6;
    if (lane == 0) red[wv] = v;
    __syncthreads();
    if (threadIdx.x == 0) {
        float sum = 0.f;
        for (int w = 0; w < THREADS / 64; ++w) sum += red[w];
        atomicAdd(out, sum);
    }
}

extern "C" void kernel_launch(void* const* d_in, const int* in_sizes, int n_in,
                              void* d_out, int out_size, void* d_ws, size_t ws_size,
                              hipStream_t stream) {
    const float* recon_x = (const float*)d_in[0];
    const float* x       = (const float*)d_in[1];
    const float* mu      = (const float*)d_in[2];
    const float* logvar  = (const float*)d_in[3];
    float* out = (float*)d_out;
    float* ws  = (float*)d_ws;   // needs 8 MB

    // d_out re-poisoned before every replay; zero the single accumulator.
    hipMemsetAsync(out, 0, sizeof(float), stream);

    chamfer_part<<<NBATCH * 2 * NCHUNK, THREADS, 0, stream>>>(recon_x, x, ws);
    reduce_kernel<<<1024, THREADS, 0, stream>>>(ws, mu, logvar, out);
}